// Round 13
// baseline (775.711 us; speedup 1.0000x reference)
//
#include <hip/hip_runtime.h>
#include <stdint.h>

#define NROWS 8192
#define KCODES 8192
#define DIM 512
#define BETA 0.25f

// fallback fp32 path tiling
#define BM 128
#define BN 128
#define BD 16
#define KCHUNK 512

// fast path: hi*hi screen error <= ~4e-4 worst-case; margin = 2x
#define MARGIN_T 8.0e-4f
#define MAXCAND 32

typedef unsigned long long u64;
typedef __attribute__((ext_vector_type(8))) short bf16x8;
typedef __attribute__((ext_vector_type(4))) float f32x4;
typedef __attribute__((ext_vector_type(4))) unsigned short us4;

// ---------------- shared helpers ----------------

__device__ inline unsigned short f2bf_rne(float x) {
    union { float f; unsigned u; } v; v.f = x;
    unsigned r = v.u + 0x7FFFu + ((v.u >> 16) & 1u);
    return (unsigned short)(r >> 16);
}
__device__ inline bool lexlt(float av, int ai, float bv, int bi) {
    return (av < bv) || (av == bv && ai < bi);
}
__device__ inline void ins2(float& v1, int& i1, float& v2, int& i2, float nv, int ni) {
    if (lexlt(nv, ni, v1, i1)) { v2 = v1; i2 = i1; v1 = nv; i1 = ni; }
    else if (lexlt(nv, ni, v2, i2)) { v2 = nv; i2 = ni; }
}

// ---------------- common: numpy-exact row norm ----------------
__global__ __launch_bounds__(256) void rownorm_kernel(const float* __restrict__ lat,
                                                      float* __restrict__ Srow) {
    __shared__ float buf[4][DIM];
    const int w = threadIdx.x >> 6;
    const int lane = threadIdx.x & 63;
    const int n = blockIdx.x * 4 + w;
    {
        const float4* p = (const float4*)(lat + (size_t)n * DIM);
        float4 v0 = p[lane * 2];
        float4 v1 = p[lane * 2 + 1];
        float4* q = (float4*)buf[w];
        q[lane * 2] = v0;
        q[lane * 2 + 1] = v1;
    }
    __syncthreads();
    if (lane < 32) {
        const int m = lane >> 3;
        const int j = lane & 7;
        const float* b = buf[w] + 128 * m + j;
        float r = b[0] * b[0];
        #pragma unroll
        for (int t = 1; t < 16; ++t) { float x = b[8 * t]; r += x * x; }
        float s1 = r + __shfl_down(r, 1);
        float s2 = s1 + __shfl_down(s1, 2);
        float s3 = s2 + __shfl_down(s2, 4);
        float x0 = s3 + __shfl_down(s3, 8);
        float S = x0 + __shfl_down(x0, 16);
        if (lane == 0) Srow[n] = S;
    }
}

// ================= FAST PATH =================

// f32 -> bf16 hi, PRE-TILED + PRE-SWIZZLED (identical to round 10):
//   tiled[(panel*8 + kt)*1024 + r*8 + cdst] (16B chunks)
//     = src[panel*128 + r][kt*64 + (cdst ^ (r&7))*8 .. +8]   (bf16)
__global__ __launch_bounds__(256) void convert_kernel(
        const float* __restrict__ lat, const float* __restrict__ cb,
        unsigned short* __restrict__ Atile, unsigned short* __restrict__ Btile,
        float* __restrict__ loss_accum) {
    size_t t = (size_t)blockIdx.x * 256 + threadIdx.x;   // one 8-elem chunk each
    if (t == 0) *loss_accum = 0.0f;
    const size_t half = (size_t)NROWS * 64;              // chunks per matrix
    const float* src; unsigned short* dst;
    if (t < half) { src = lat; dst = Atile; }
    else { src = cb; dst = Btile; t -= half; }
    const int row   = (int)(t >> 6);       // 0..8191
    const int csrc  = (int)(t & 63);       // source chunk 0..63
    const int panel = row >> 7;            // 0..63
    const int r     = row & 127;
    const int kt    = csrc >> 3;           // 0..7
    const int cdst  = (csrc & 7) ^ (r & 7);
    const float4 v0 = *(const float4*)(src + (size_t)row * DIM + csrc * 8);
    const float4 v1 = *(const float4*)(src + (size_t)row * DIM + csrc * 8 + 4);
    us4 h0, h1;
    h0.x = f2bf_rne(v0.x); h0.y = f2bf_rne(v0.y); h0.z = f2bf_rne(v0.z); h0.w = f2bf_rne(v0.w);
    h1.x = f2bf_rne(v1.x); h1.y = f2bf_rne(v1.y); h1.z = f2bf_rne(v1.z); h1.w = f2bf_rne(v1.w);
    unsigned short* o = dst + (((size_t)(panel * 8 + kt) * 128 + r) * 8 + cdst) * 8;
    *(us4*)o = h0;
    *(us4*)(o + 4) = h1;
}

// 256x256 block tile, 8 waves (2x4, 128x64 each), single 64 KiB LDS,
// PLAIN coalesced global loads -> regs -> immediate ds_write_b128 (no
// cross-phase register liveness -> no spill), 2 barriers per K-step.
// Raises intensity to ~131 FLOP/B (vs 32 register-only) while using the
// plain-load path (>=3.2 TB/s measured R12) instead of global_load_lds
// (~0.8 TB/s measured R8). Screen = hi*hi bf16; margin + exact rescore.
__global__ __launch_bounds__(512) void mfma_dist_kernel(
        const unsigned short* __restrict__ Atile, const unsigned short* __restrict__ Btile,
        float4* __restrict__ top2) {
    __shared__ unsigned short sA[256][64];   // 32 KiB
    __shared__ unsigned short sB[256][64];   // 32 KiB
    // XCD supertile: xcd = bid&7 owns by in [xcd*4, xcd*4+4); bx in groups of 4.
    const int bid = blockIdx.x;
    const int xcd = bid & 7;
    const int j = bid >> 3;            // 0..127
    const int st = j >> 4;             // 0..7
    const int tt = j & 15;
    const int bx = st * 4 + (tt & 3);  // 0..31
    const int by = xcd * 4 + (tt >> 2);// 0..31
    const int row0 = bx * 256, col0 = by * 256;
    const int tid = threadIdx.x;
    const int w = tid >> 6, l = tid & 63;
    const int wm = w >> 2, wn = w & 3;          // 2 x 4 wave grid
    const int g = l >> 4, c = l & 15;

    f32x4 acc[8][4];
    #pragma unroll
    for (int a = 0; a < 8; ++a)
        #pragma unroll
        for (int b = 0; b < 4; ++b)
            acc[a][b] = (f32x4){0.f, 0.f, 0.f, 0.f};

    const int4* Ag = (const int4*)Atile;
    const int4* Bg = (const int4*)Btile;
    int4* dA = (int4*)&sA[0][0];
    int4* dB = (int4*)&sB[0][0];
    // chunk bases for the two 128-row panels of each 256-row tile
    const size_t pa0 = (size_t)(bx * 2 + 0) * 8 * 1024;
    const size_t pa1 = (size_t)(bx * 2 + 1) * 8 * 1024;
    const size_t pb0 = (size_t)(by * 2 + 0) * 8 * 1024;
    const size_t pb1 = (size_t)(by * 2 + 1) * 8 * 1024;

    for (int kt = 0; kt < 8; ++kt) {
        const size_t o = (size_t)kt * 1024;
        // stage: 8 independent coalesced loads -> 8 ds_writes, no liveness
        // beyond this phase
        int4 a0 = Ag[pa0 + o + tid];
        int4 a1 = Ag[pa0 + o + tid + 512];
        int4 a2 = Ag[pa1 + o + tid];
        int4 a3 = Ag[pa1 + o + tid + 512];
        int4 b0 = Bg[pb0 + o + tid];
        int4 b1 = Bg[pb0 + o + tid + 512];
        int4 b2 = Bg[pb1 + o + tid];
        int4 b3 = Bg[pb1 + o + tid + 512];
        dA[tid] = a0; dA[tid + 512] = a1; dA[tid + 1024] = a2; dA[tid + 1536] = a3;
        dB[tid] = b0; dB[tid + 512] = b1; dB[tid + 1024] = b2; dB[tid + 1536] = b3;
        __syncthreads();   // tile visible
        #pragma unroll
        for (int kk = 0; kk < 2; ++kk) {
            const int colbase = kk * 32 + g * 8;
            bf16x8 af[8], bfr[4];
            #pragma unroll
            for (int f = 0; f < 8; ++f) {
                int ra = wm * 128 + f * 16 + c;
                int ca = colbase ^ ((ra & 7) << 3);   // swizzled read
                af[f] = *(const bf16x8*)&sA[ra][ca];
            }
            #pragma unroll
            for (int f = 0; f < 4; ++f) {
                int rb = wn * 64 + f * 16 + c;
                int cb2 = colbase ^ ((rb & 7) << 3);
                bfr[f] = *(const bf16x8*)&sB[rb][cb2];
            }
            #pragma unroll
            for (int fm = 0; fm < 8; ++fm)
                #pragma unroll
                for (int fn = 0; fn < 4; ++fn)
                    acc[fm][fn] = __builtin_amdgcn_mfma_f32_16x16x32_bf16(
                        af[fm], bfr[fn], acc[fm][fn], 0, 0, 0);
        }
        __syncthreads();   // all reads done; safe to overwrite
    }

    // epilogue: per-row top-2 over this wave's 64 codes (lex (t,idx)); t=-2*acc
    #pragma unroll
    for (int fm = 0; fm < 8; ++fm) {
        #pragma unroll
        for (int r = 0; r < 4; ++r) {
            float v1 = -2.0f * acc[fm][0][r];
            int i1 = col0 + wn * 64 + c;
            float v2 = 3.4e38f; int i2 = 0x7FFFFFFF;
            #pragma unroll
            for (int fn = 1; fn < 4; ++fn) {
                float nv = -2.0f * acc[fm][fn][r];
                int ni = col0 + wn * 64 + fn * 16 + c;
                ins2(v1, i1, v2, i2, nv, ni);
            }
            #pragma unroll
            for (int mask = 1; mask <= 8; mask <<= 1) {
                float o1 = __shfl_xor(v1, mask); int oi1 = __shfl_xor(i1, mask);
                float o2 = __shfl_xor(v2, mask); int oi2 = __shfl_xor(i2, mask);
                ins2(v1, i1, v2, i2, o1, oi1);
                ins2(v1, i1, v2, i2, o2, oi2);
            }
            if (c == 0) {
                int row = row0 + wm * 128 + fm * 16 + g * 4 + r;
                float4 e;
                e.x = v1; e.y = __int_as_float(i1);
                e.z = v2; e.w = __int_as_float(i2);
                top2[(size_t)row * 128 + by * 4 + wn] = e;
            }
        }
    }
}

// per row: global approx min over 256 stored entries, margin candidates,
// exact numpy-fp32-chain rescore, lexicographic winner.
__global__ __launch_bounds__(256) void select_rescore_kernel(
        const float* __restrict__ lat, const float* __restrict__ cb,
        const float* __restrict__ Srow, const float4* __restrict__ top2,
        int* __restrict__ idxfinal) {
    __shared__ float fr[DIM];
    __shared__ float svals[128];
    __shared__ int sidx[128];
    __shared__ int scnt;
    __shared__ int scand[MAXCAND];
    __shared__ float cs[MAXCAND];
    __shared__ int ck[MAXCAND];
    const int n = blockIdx.x;
    const int t = threadIdx.x;

    fr[t] = lat[(size_t)n * DIM + t];
    fr[t + 256] = lat[(size_t)n * DIM + t + 256];
    if (t == 0) scnt = 0;

    float4 e;
    if (t < 128) {
        e = top2[(size_t)n * 128 + t];
        float pv = e.x; int pi = __float_as_int(e.y);
        int e2 = __float_as_int(e.w);
        if (lexlt(e.z, e2, pv, pi)) { pv = e.z; pi = e2; }
        svals[t] = pv; sidx[t] = pi;
    }
    __syncthreads();
    for (int s = 64; s > 0; s >>= 1) {
        if (t < s && lexlt(svals[t + s], sidx[t + s], svals[t], sidx[t])) {
            svals[t] = svals[t + s]; sidx[t] = sidx[t + s];
        }
        __syncthreads();
    }
    const float gthr = svals[0] + MARGIN_T;
    __syncthreads();
    if (t < 128) {
        if (e.x <= gthr) {
            int p = atomicAdd(&scnt, 1);
            if (p < MAXCAND) scand[p] = __float_as_int(e.y);
        }
        if (e.z <= gthr) {
            int p = atomicAdd(&scnt, 1);
            if (p < MAXCAND) scand[p] = __float_as_int(e.w);
        }
    }
    __syncthreads();
    int m = scnt < MAXCAND ? scnt : MAXCAND;
    if (t < m) {
        int k = scand[t];
        const float* crow = cb + (size_t)k * DIM;
        float acc = 0.0f;
        for (int d = 0; d < DIM; d += 4) {   // exact ascending-d FMA chain
            float4 b = *(const float4*)(crow + d);
            acc = __builtin_fmaf(fr[d + 0], b.x, acc);
            acc = __builtin_fmaf(fr[d + 1], b.y, acc);
            acc = __builtin_fmaf(fr[d + 2], b.z, acc);
            acc = __builtin_fmaf(fr[d + 3], b.w, acc);
        }
        cs[t] = __builtin_fmaf(-2.0f, acc, Srow[n]);
        ck[t] = k;
    }
    __syncthreads();
    if (t == 0) {
        float bv = cs[0]; int bi = ck[0];
        for (int q = 1; q < m; ++q)
            if (lexlt(cs[q], ck[q], bv, bi)) { bv = cs[q]; bi = ck[q]; }
        idxfinal[n] = bi;
    }
}

__global__ void finalize_idx_kernel(const float* __restrict__ lat,
                                    const float* __restrict__ cb,
                                    const int* __restrict__ idxfinal,
                                    float* __restrict__ out_q,
                                    float* __restrict__ out_idx,
                                    float* __restrict__ loss_accum) {
    int n = blockIdx.x;
    int t = threadIdx.x;
    int idx = idxfinal[n];
    const float2 q = ((const float2*)(cb + (size_t)idx * DIM))[t];
    const float2 l = ((const float2*)(lat + (size_t)n * DIM))[t];
    ((float2*)(out_q + (size_t)n * DIM))[t] = q;
    float dx = l.x - q.x, dy = l.y - q.y;
    float local = dx * dx + dy * dy;
    #pragma unroll
    for (int off = 32; off > 0; off >>= 1) local += __shfl_down(local, off);
    __shared__ float wsum[4];
    if ((t & 63) == 0) wsum[t >> 6] = local;
    __syncthreads();
    if (t == 0) {
        atomicAdd(loss_accum, wsum[0] + wsum[1] + wsum[2] + wsum[3]);
        out_idx[n] = (float)idx;
    }
}

// ================= FALLBACK (round-3 verified) =================

__global__ void init_ws_kernel(u64* __restrict__ best, float* __restrict__ loss_accum) {
    int i = blockIdx.x * blockDim.x + threadIdx.x;
    if (i < NROWS) best[i] = 0xFFFFFFFFFFFFFFFFULL;
    if (i == 0) *loss_accum = 0.0f;
}

__global__ __launch_bounds__(256) void dist_argmin_kernel(
        const float* __restrict__ lat, const float* __restrict__ cb,
        const float* __restrict__ Srow, u64* __restrict__ best) {
    __shared__ float As[BD][BM];
    __shared__ float Bs[BD][BN];
    const int tid = threadIdx.x;
    const int tx = tid & 15;
    const int ty = tid >> 4;
    const int row0 = blockIdx.x * BM;
    const int kbase = blockIdx.y * KCHUNK;

    int rowid[8];
    float Sr[8];
    #pragma unroll
    for (int i = 0; i < 8; ++i) {
        rowid[i] = row0 + ((i < 4) ? (ty * 4 + i) : (64 + ty * 4 + (i - 4)));
        Sr[i] = Srow[rowid[i]];
    }
    float bval[8];
    int bidx[8];
    #pragma unroll
    for (int i = 0; i < 8; ++i) { bval[i] = 3.4e38f; bidx[i] = 0; }

    for (int kt = 0; kt < KCHUNK; kt += BN) {
        float acc[8][8];
        #pragma unroll
        for (int i = 0; i < 8; ++i)
            #pragma unroll
            for (int j = 0; j < 8; ++j) acc[i][j] = 0.0f;
        for (int d0 = 0; d0 < DIM; d0 += BD) {
            __syncthreads();
            #pragma unroll
            for (int u = 0; u < 2; ++u) {
                int f = tid * 2 + u;
                int r = f >> 2;
                int dq = (f & 3) * 4;
                float4 va = *(const float4*)(lat + (size_t)(row0 + r) * DIM + d0 + dq);
                As[dq + 0][r] = va.x; As[dq + 1][r] = va.y;
                As[dq + 2][r] = va.z; As[dq + 3][r] = va.w;
                float4 vb = *(const float4*)(cb + (size_t)(kbase + kt + r) * DIM + d0 + dq);
                Bs[dq + 0][r] = vb.x; Bs[dq + 1][r] = vb.y;
                Bs[dq + 2][r] = vb.z; Bs[dq + 3][r] = vb.w;
            }
            __syncthreads();
            #pragma unroll
            for (int dd = 0; dd < BD; ++dd) {
                float4 a0 = *(const float4*)&As[dd][ty * 4];
                float4 a1 = *(const float4*)&As[dd][64 + ty * 4];
                float4 b0 = *(const float4*)&Bs[dd][tx * 4];
                float4 b1 = *(const float4*)&Bs[dd][64 + tx * 4];
                float av[8] = {a0.x, a0.y, a0.z, a0.w, a1.x, a1.y, a1.z, a1.w};
                float bv[8] = {b0.x, b0.y, b0.z, b0.w, b1.x, b1.y, b1.z, b1.w};
                #pragma unroll
                for (int i = 0; i < 8; ++i)
                    #pragma unroll
                    for (int j = 0; j < 8; ++j)
                        acc[i][j] = __builtin_fmaf(av[i], bv[j], acc[i][j]);
            }
        }
        #pragma unroll
        for (int j = 0; j < 8; ++j) {
            int cj = (j < 4) ? (tx * 4 + j) : (64 + tx * 4 + (j - 4));
            int k = kbase + kt + cj;
            #pragma unroll
            for (int i = 0; i < 8; ++i) {
                float s = __builtin_fmaf(-2.0f, acc[i][j], Sr[i]);
                if (s < bval[i]) { bval[i] = s; bidx[i] = k; }
            }
        }
    }
    #pragma unroll
    for (int i = 0; i < 8; ++i) {
        float v = bval[i];
        int ix = bidx[i];
        #pragma unroll
        for (int off = 8; off > 0; off >>= 1) {
            float ov = __shfl_xor(v, off, 16);
            int oi = __shfl_xor(ix, off, 16);
            if (ov < v || (ov == v && oi < ix)) { v = ov; ix = oi; }
        }
        if (tx == 0) {
            unsigned u = __float_as_uint(v);
            unsigned key = (u & 0x80000000u) ? ~u : (u | 0x80000000u);
            u64 pk = ((u64)key << 32) | (unsigned)ix;
            atomicMin(&best[rowid[i]], pk);
        }
    }
}

__global__ void finalize_kernel(const float* __restrict__ lat,
                                const float* __restrict__ cb,
                                const u64* __restrict__ best,
                                float* __restrict__ out_q,
                                float* __restrict__ out_idx,
                                float* __restrict__ loss_accum) {
    int n = blockIdx.x;
    int t = threadIdx.x;
    int idx = (int)(best[n] & 0xFFFFFFFFULL);
    const float2 q = ((const float2*)(cb + (size_t)idx * DIM))[t];
    const float2 l = ((const float2*)(lat + (size_t)n * DIM))[t];
    ((float2*)(out_q + (size_t)n * DIM))[t] = q;
    float dx = l.x - q.x, dy = l.y - q.y;
    float local = dx * dx + dy * dy;
    #pragma unroll
    for (int off = 32; off > 0; off >>= 1) local += __shfl_down(local, off);
    __shared__ float wsum[4];
    if ((t & 63) == 0) wsum[t >> 6] = local;
    __syncthreads();
    if (t == 0) {
        atomicAdd(loss_accum, wsum[0] + wsum[1] + wsum[2] + wsum[3]);
        out_idx[n] = (float)idx;
    }
}

__global__ void write_loss_kernel(const float* __restrict__ loss_accum,
                                  float* __restrict__ out_loss) {
    *out_loss = (1.0f + BETA) * (*loss_accum) * (1.0f / (float)((size_t)NROWS * DIM));
}

// ---------------- launch ----------------

extern "C" void kernel_launch(void* const* d_in, const int* in_sizes, int n_in,
                              void* d_out, int out_size, void* d_ws, size_t ws_size,
                              hipStream_t stream) {
    const float* lat = (const float*)d_in[0];   // [8,1024,512] f32
    const float* cb  = (const float*)d_in[1];   // [8192,512] f32

    float* out = (float*)d_out;
    float* out_q    = out;
    float* out_loss = out + (size_t)NROWS * DIM;
    float* out_idx  = out_loss + 1;

    char* ws = (char*)d_ws;

    // fast-path layout (same sizes as rounds 7-12)
    const size_t MATB = (size_t)NROWS * DIM * 2;            // 8 MiB per bf16 matrix
    unsigned short* Atile = (unsigned short*)(ws);
    unsigned short* Btile = (unsigned short*)(ws + MATB);
    float4* top2        = (float4*)(ws + 2 * MATB);         // 16 MiB
    char* tail          = ws + 2 * MATB + (size_t)NROWS * 128 * 16;
    float* SrowF        = (float*)tail;                     // 32 KiB
    int*   idxfinal     = (int*)(tail + 32768);             // 32 KiB
    float* lossF        = (float*)(tail + 65536);           // 4 B
    const size_t REQ    = (size_t)(tail - ws) + 65536 + 64;

    if (ws_size >= REQ) {
        hipLaunchKernelGGL(convert_kernel, dim3(2 * NROWS * 64 / 256), dim3(256), 0, stream,
                           lat, cb, Atile, Btile, lossF);
        hipLaunchKernelGGL(rownorm_kernel, dim3(NROWS / 4), dim3(256), 0, stream, lat, SrowF);
        hipLaunchKernelGGL(mfma_dist_kernel, dim3((NROWS / 256) * (KCODES / 256)), dim3(512),
                           0, stream, Atile, Btile, top2);
        hipLaunchKernelGGL(select_rescore_kernel, dim3(NROWS), dim3(256), 0, stream,
                           lat, cb, SrowF, top2, idxfinal);
        hipLaunchKernelGGL(finalize_idx_kernel, dim3(NROWS), dim3(256), 0, stream,
                           lat, cb, idxfinal, out_q, out_idx, lossF);
        hipLaunchKernelGGL(write_loss_kernel, dim3(1), dim3(1), 0, stream, lossF, out_loss);
    } else {
        // round-3 verified fallback
        u64*   best       = (u64*)(ws + 0);
        float* Srow       = (float*)(ws + 65536);
        float* loss_accum = (float*)(ws + 98304);
        hipLaunchKernelGGL(init_ws_kernel, dim3(32), dim3(256), 0, stream, best, loss_accum);
        hipLaunchKernelGGL(rownorm_kernel, dim3(NROWS / 4), dim3(256), 0, stream, lat, Srow);
        hipLaunchKernelGGL(dist_argmin_kernel, dim3(NROWS / BM, KCODES / KCHUNK), dim3(256),
                           0, stream, lat, cb, Srow, best);
        hipLaunchKernelGGL(finalize_kernel, dim3(NROWS), dim3(256), 0, stream,
                           lat, cb, best, out_q, out_idx, loss_accum);
        hipLaunchKernelGGL(write_loss_kernel, dim3(1), dim3(1), 0, stream, loss_accum, out_loss);
    }
}

// Round 14
// 773.210 us; speedup vs baseline: 1.0032x; 1.0032x over previous
//
#include <hip/hip_runtime.h>
#include <stdint.h>

#define NROWS 8192
#define KCODES 8192
#define DIM 512
#define BETA 0.25f

// fallback fp32 path tiling
#define BM 128
#define BN 128
#define BD 16
#define KCHUNK 512

// fast path: hi*hi screen error <= ~4e-4 worst-case; margin = 2x
#define MARGIN_T 8.0e-4f
#define MAXCAND 32

typedef unsigned long long u64;
typedef __attribute__((ext_vector_type(8))) short bf16x8;
typedef __attribute__((ext_vector_type(4))) float f32x4;
typedef __attribute__((ext_vector_type(4))) unsigned short us4;

// ---------------- shared helpers ----------------

__device__ inline unsigned short f2bf_rne(float x) {
    union { float f; unsigned u; } v; v.f = x;
    unsigned r = v.u + 0x7FFFu + ((v.u >> 16) & 1u);
    return (unsigned short)(r >> 16);
}
__device__ inline bool lexlt(float av, int ai, float bv, int bi) {
    return (av < bv) || (av == bv && ai < bi);
}
__device__ inline void ins2(float& v1, int& i1, float& v2, int& i2, float nv, int ni) {
    if (lexlt(nv, ni, v1, i1)) { v2 = v1; i2 = i1; v1 = nv; i1 = ni; }
    else if (lexlt(nv, ni, v2, i2)) { v2 = nv; i2 = ni; }
}

// ---------------- common: numpy-exact row norm ----------------
__global__ __launch_bounds__(256) void rownorm_kernel(const float* __restrict__ lat,
                                                      float* __restrict__ Srow) {
    __shared__ float buf[4][DIM];
    const int w = threadIdx.x >> 6;
    const int lane = threadIdx.x & 63;
    const int n = blockIdx.x * 4 + w;
    {
        const float4* p = (const float4*)(lat + (size_t)n * DIM);
        float4 v0 = p[lane * 2];
        float4 v1 = p[lane * 2 + 1];
        float4* q = (float4*)buf[w];
        q[lane * 2] = v0;
        q[lane * 2 + 1] = v1;
    }
    __syncthreads();
    if (lane < 32) {
        const int m = lane >> 3;
        const int j = lane & 7;
        const float* b = buf[w] + 128 * m + j;
        float r = b[0] * b[0];
        #pragma unroll
        for (int t = 1; t < 16; ++t) { float x = b[8 * t]; r += x * x; }
        float s1 = r + __shfl_down(r, 1);
        float s2 = s1 + __shfl_down(s1, 2);
        float s3 = s2 + __shfl_down(s2, 4);
        float x0 = s3 + __shfl_down(s3, 8);
        float S = x0 + __shfl_down(x0, 16);
        if (lane == 0) Srow[n] = S;
    }
}

// ================= FAST PATH =================

// f32 -> bf16 hi, PRE-TILED + PRE-SWIZZLED (identical to rounds 10-13):
//   tiled[(panel*8 + kt)*1024 + r*8 + cdst] (16B chunks)
//     = src[panel*128 + r][kt*64 + (cdst ^ (r&7))*8 .. +8]   (bf16)
__global__ __launch_bounds__(256) void convert_kernel(
        const float* __restrict__ lat, const float* __restrict__ cb,
        unsigned short* __restrict__ Atile, unsigned short* __restrict__ Btile,
        float* __restrict__ loss_accum) {
    size_t t = (size_t)blockIdx.x * 256 + threadIdx.x;   // one 8-elem chunk each
    if (t == 0) *loss_accum = 0.0f;
    const size_t half = (size_t)NROWS * 64;              // chunks per matrix
    const float* src; unsigned short* dst;
    if (t < half) { src = lat; dst = Atile; }
    else { src = cb; dst = Btile; t -= half; }
    const int row   = (int)(t >> 6);       // 0..8191
    const int csrc  = (int)(t & 63);       // source chunk 0..63
    const int panel = row >> 7;            // 0..63
    const int r     = row & 127;
    const int kt    = csrc >> 3;           // 0..7
    const int cdst  = (csrc & 7) ^ (r & 7);
    const float4 v0 = *(const float4*)(src + (size_t)row * DIM + csrc * 8);
    const float4 v1 = *(const float4*)(src + (size_t)row * DIM + csrc * 8 + 4);
    us4 h0, h1;
    h0.x = f2bf_rne(v0.x); h0.y = f2bf_rne(v0.y); h0.z = f2bf_rne(v0.z); h0.w = f2bf_rne(v0.w);
    h1.x = f2bf_rne(v1.x); h1.y = f2bf_rne(v1.y); h1.z = f2bf_rne(v1.z); h1.w = f2bf_rne(v1.w);
    unsigned short* o = dst + (((size_t)(panel * 8 + kt) * 128 + r) * 8 + cdst) * 8;
    *(us4*)o = h0;
    *(us4*)(o + 4) = h1;
}

// PERSISTENT pipelined screen: 256 blocks (1/CU, all resident), 512 threads,
// each block owns 4 tiles of 256x256 (32 K-steps). Double-buffered LDS
// (128 KiB), ONE barrier per K-step:
//   issue loads(k+1)->regs; compute buf[cur]; ds_write regs->buf[cur^1]; bar.
// __launch_bounds__(512,1) frees the allocator to 256 VGPRs so the 8 staging
// int4 regs that live across compute do NOT spill (round-11 failure mode).
// Screen = hi*hi bf16; margin + exact rescore downstream (unchanged).
__global__ __launch_bounds__(512, 1) void mfma_dist_kernel(
        const unsigned short* __restrict__ Atile, const unsigned short* __restrict__ Btile,
        float4* __restrict__ top2) {
    __shared__ unsigned short sA[2][256][64];   // 64 KiB
    __shared__ unsigned short sB[2][256][64];   // 64 KiB
    // XCD tile ownership: xcd = bid&7 owns by in [xcd*4, xcd*4+4).
    const int bid = blockIdx.x;        // 0..255
    const int xcd = bid & 7;
    const int ci  = bid >> 3;          // 0..31
    const int bx0 = (ci & 15) * 2;     // 0,2,..,30
    const int by0 = xcd * 4 + (ci >> 4) * 2;
    const int tid = threadIdx.x;
    const int w = tid >> 6, l = tid & 63;
    const int wm = w >> 2, wn = w & 3;          // 2 x 4 wave grid
    const int g = l >> 4, c = l & 15;

    const int4* Ag = (const int4*)Atile;
    const int4* Bg = (const int4*)Btile;

    for (int t = 0; t < 4; ++t) {
        const int bx = bx0 + (t & 1);
        const int by = by0 + (t >> 1);
        const int row0 = bx * 256, col0 = by * 256;
        const size_t pa0 = (size_t)(bx * 2 + 0) * 8 * 1024;
        const size_t pa1 = (size_t)(bx * 2 + 1) * 8 * 1024;
        const size_t pb0 = (size_t)(by * 2 + 0) * 8 * 1024;
        const size_t pb1 = (size_t)(by * 2 + 1) * 8 * 1024;

        f32x4 acc[8][4];
        #pragma unroll
        for (int a = 0; a < 8; ++a)
            #pragma unroll
            for (int b = 0; b < 4; ++b)
                acc[a][b] = (f32x4){0.f, 0.f, 0.f, 0.f};

        // staging registers (live across compute; (512,1) prevents spill)
        int4 a0, a1, a2, a3, b0, b1, b2, b3;

        // prologue: stage step 0 into buf0
        {
            a0 = Ag[pa0 + tid];       a1 = Ag[pa0 + tid + 512];
            a2 = Ag[pa1 + tid];       a3 = Ag[pa1 + tid + 512];
            b0 = Bg[pb0 + tid];       b1 = Bg[pb0 + tid + 512];
            b2 = Bg[pb1 + tid];       b3 = Bg[pb1 + tid + 512];
            int4* dA = (int4*)&sA[0][0][0];
            int4* dB = (int4*)&sB[0][0][0];
            dA[tid] = a0; dA[tid + 512] = a1; dA[tid + 1024] = a2; dA[tid + 1536] = a3;
            dB[tid] = b0; dB[tid + 512] = b1; dB[tid + 1024] = b2; dB[tid + 1536] = b3;
        }
        __syncthreads();

        int cur = 0;
        for (int kt = 0; kt < 8; ++kt) {
            if (kt < 7) {   // issue next step's loads: latency hides under compute
                const size_t o = (size_t)(kt + 1) * 1024;
                a0 = Ag[pa0 + o + tid];   a1 = Ag[pa0 + o + tid + 512];
                a2 = Ag[pa1 + o + tid];   a3 = Ag[pa1 + o + tid + 512];
                b0 = Bg[pb0 + o + tid];   b1 = Bg[pb0 + o + tid + 512];
                b2 = Bg[pb1 + o + tid];   b3 = Bg[pb1 + o + tid + 512];
            }
            // compute on buf[cur]
            #pragma unroll
            for (int kk = 0; kk < 2; ++kk) {
                const int colbase = kk * 32 + g * 8;
                bf16x8 af[8], bfr[4];
                #pragma unroll
                for (int f = 0; f < 8; ++f) {
                    int ra = wm * 128 + f * 16 + c;
                    int ca = colbase ^ ((ra & 7) << 3);   // swizzled read
                    af[f] = *(const bf16x8*)&sA[cur][ra][ca];
                }
                #pragma unroll
                for (int f = 0; f < 4; ++f) {
                    int rb = wn * 64 + f * 16 + c;
                    int cb2 = colbase ^ ((rb & 7) << 3);
                    bfr[f] = *(const bf16x8*)&sB[cur][rb][cb2];
                }
                #pragma unroll
                for (int fm = 0; fm < 8; ++fm)
                    #pragma unroll
                    for (int fn = 0; fn < 4; ++fn)
                        acc[fm][fn] = __builtin_amdgcn_mfma_f32_16x16x32_bf16(
                            af[fm], bfr[fn], acc[fm][fn], 0, 0, 0);
            }
            if (kt < 7) {   // write to the OTHER buffer: no race with cur readers
                int4* dA = (int4*)&sA[cur ^ 1][0][0];
                int4* dB = (int4*)&sB[cur ^ 1][0][0];
                dA[tid] = a0; dA[tid + 512] = a1; dA[tid + 1024] = a2; dA[tid + 1536] = a3;
                dB[tid] = b0; dB[tid + 512] = b1; dB[tid + 1024] = b2; dB[tid + 1536] = b3;
            }
            __syncthreads();   // next buffer visible; cur free after next step
            cur ^= 1;
        }

        // epilogue: per-row top-2 over this wave's 64 codes (lex (t,idx)); t=-2*acc
        #pragma unroll
        for (int fm = 0; fm < 8; ++fm) {
            #pragma unroll
            for (int r = 0; r < 4; ++r) {
                float v1 = -2.0f * acc[fm][0][r];
                int i1 = col0 + wn * 64 + c;
                float v2 = 3.4e38f; int i2 = 0x7FFFFFFF;
                #pragma unroll
                for (int fn = 1; fn < 4; ++fn) {
                    float nv = -2.0f * acc[fm][fn][r];
                    int ni = col0 + wn * 64 + fn * 16 + c;
                    ins2(v1, i1, v2, i2, nv, ni);
                }
                #pragma unroll
                for (int mask = 1; mask <= 8; mask <<= 1) {
                    float o1 = __shfl_xor(v1, mask); int oi1 = __shfl_xor(i1, mask);
                    float o2 = __shfl_xor(v2, mask); int oi2 = __shfl_xor(i2, mask);
                    ins2(v1, i1, v2, i2, o1, oi1);
                    ins2(v1, i1, v2, i2, o2, oi2);
                }
                if (c == 0) {
                    int row = row0 + wm * 128 + fm * 16 + g * 4 + r;
                    float4 e;
                    e.x = v1; e.y = __int_as_float(i1);
                    e.z = v2; e.w = __int_as_float(i2);
                    top2[(size_t)row * 128 + by * 4 + wn] = e;
                }
            }
        }
        __syncthreads();   // tile boundary: LDS reuse safe
    }
}

// per row: global approx min over 256 stored entries, margin candidates,
// exact numpy-fp32-chain rescore, lexicographic winner.
__global__ __launch_bounds__(256) void select_rescore_kernel(
        const float* __restrict__ lat, const float* __restrict__ cb,
        const float* __restrict__ Srow, const float4* __restrict__ top2,
        int* __restrict__ idxfinal) {
    __shared__ float fr[DIM];
    __shared__ float svals[128];
    __shared__ int sidx[128];
    __shared__ int scnt;
    __shared__ int scand[MAXCAND];
    __shared__ float cs[MAXCAND];
    __shared__ int ck[MAXCAND];
    const int n = blockIdx.x;
    const int t = threadIdx.x;

    fr[t] = lat[(size_t)n * DIM + t];
    fr[t + 256] = lat[(size_t)n * DIM + t + 256];
    if (t == 0) scnt = 0;

    float4 e;
    if (t < 128) {
        e = top2[(size_t)n * 128 + t];
        float pv = e.x; int pi = __float_as_int(e.y);
        int e2 = __float_as_int(e.w);
        if (lexlt(e.z, e2, pv, pi)) { pv = e.z; pi = e2; }
        svals[t] = pv; sidx[t] = pi;
    }
    __syncthreads();
    for (int s = 64; s > 0; s >>= 1) {
        if (t < s && lexlt(svals[t + s], sidx[t + s], svals[t], sidx[t])) {
            svals[t] = svals[t + s]; sidx[t] = sidx[t + s];
        }
        __syncthreads();
    }
    const float gthr = svals[0] + MARGIN_T;
    __syncthreads();
    if (t < 128) {
        if (e.x <= gthr) {
            int p = atomicAdd(&scnt, 1);
            if (p < MAXCAND) scand[p] = __float_as_int(e.y);
        }
        if (e.z <= gthr) {
            int p = atomicAdd(&scnt, 1);
            if (p < MAXCAND) scand[p] = __float_as_int(e.w);
        }
    }
    __syncthreads();
    int m = scnt < MAXCAND ? scnt : MAXCAND;
    if (t < m) {
        int k = scand[t];
        const float* crow = cb + (size_t)k * DIM;
        float acc = 0.0f;
        for (int d = 0; d < DIM; d += 4) {   // exact ascending-d FMA chain
            float4 b = *(const float4*)(crow + d);
            acc = __builtin_fmaf(fr[d + 0], b.x, acc);
            acc = __builtin_fmaf(fr[d + 1], b.y, acc);
            acc = __builtin_fmaf(fr[d + 2], b.z, acc);
            acc = __builtin_fmaf(fr[d + 3], b.w, acc);
        }
        cs[t] = __builtin_fmaf(-2.0f, acc, Srow[n]);
        ck[t] = k;
    }
    __syncthreads();
    if (t == 0) {
        float bv = cs[0]; int bi = ck[0];
        for (int q = 1; q < m; ++q)
            if (lexlt(cs[q], ck[q], bv, bi)) { bv = cs[q]; bi = ck[q]; }
        idxfinal[n] = bi;
    }
}

__global__ void finalize_idx_kernel(const float* __restrict__ lat,
                                    const float* __restrict__ cb,
                                    const int* __restrict__ idxfinal,
                                    float* __restrict__ out_q,
                                    float* __restrict__ out_idx,
                                    float* __restrict__ loss_accum) {
    int n = blockIdx.x;
    int t = threadIdx.x;
    int idx = idxfinal[n];
    const float2 q = ((const float2*)(cb + (size_t)idx * DIM))[t];
    const float2 l = ((const float2*)(lat + (size_t)n * DIM))[t];
    ((float2*)(out_q + (size_t)n * DIM))[t] = q;
    float dx = l.x - q.x, dy = l.y - q.y;
    float local = dx * dx + dy * dy;
    #pragma unroll
    for (int off = 32; off > 0; off >>= 1) local += __shfl_down(local, off);
    __shared__ float wsum[4];
    if ((t & 63) == 0) wsum[t >> 6] = local;
    __syncthreads();
    if (t == 0) {
        atomicAdd(loss_accum, wsum[0] + wsum[1] + wsum[2] + wsum[3]);
        out_idx[n] = (float)idx;
    }
}

// ================= FALLBACK (round-3 verified) =================

__global__ void init_ws_kernel(u64* __restrict__ best, float* __restrict__ loss_accum) {
    int i = blockIdx.x * blockDim.x + threadIdx.x;
    if (i < NROWS) best[i] = 0xFFFFFFFFFFFFFFFFULL;
    if (i == 0) *loss_accum = 0.0f;
}

__global__ __launch_bounds__(256) void dist_argmin_kernel(
        const float* __restrict__ lat, const float* __restrict__ cb,
        const float* __restrict__ Srow, u64* __restrict__ best) {
    __shared__ float As[BD][BM];
    __shared__ float Bs[BD][BN];
    const int tid = threadIdx.x;
    const int tx = tid & 15;
    const int ty = tid >> 4;
    const int row0 = blockIdx.x * BM;
    const int kbase = blockIdx.y * KCHUNK;

    int rowid[8];
    float Sr[8];
    #pragma unroll
    for (int i = 0; i < 8; ++i) {
        rowid[i] = row0 + ((i < 4) ? (ty * 4 + i) : (64 + ty * 4 + (i - 4)));
        Sr[i] = Srow[rowid[i]];
    }
    float bval[8];
    int bidx[8];
    #pragma unroll
    for (int i = 0; i < 8; ++i) { bval[i] = 3.4e38f; bidx[i] = 0; }

    for (int kt = 0; kt < KCHUNK; kt += BN) {
        float acc[8][8];
        #pragma unroll
        for (int i = 0; i < 8; ++i)
            #pragma unroll
            for (int j = 0; j < 8; ++j) acc[i][j] = 0.0f;
        for (int d0 = 0; d0 < DIM; d0 += BD) {
            __syncthreads();
            #pragma unroll
            for (int u = 0; u < 2; ++u) {
                int f = tid * 2 + u;
                int r = f >> 2;
                int dq = (f & 3) * 4;
                float4 va = *(const float4*)(lat + (size_t)(row0 + r) * DIM + d0 + dq);
                As[dq + 0][r] = va.x; As[dq + 1][r] = va.y;
                As[dq + 2][r] = va.z; As[dq + 3][r] = va.w;
                float4 vb = *(const float4*)(cb + (size_t)(kbase + kt + r) * DIM + d0 + dq);
                Bs[dq + 0][r] = vb.x; Bs[dq + 1][r] = vb.y;
                Bs[dq + 2][r] = vb.z; Bs[dq + 3][r] = vb.w;
            }
            __syncthreads();
            #pragma unroll
            for (int dd = 0; dd < BD; ++dd) {
                float4 a0 = *(const float4*)&As[dd][ty * 4];
                float4 a1 = *(const float4*)&As[dd][64 + ty * 4];
                float4 b0 = *(const float4*)&Bs[dd][tx * 4];
                float4 b1 = *(const float4*)&Bs[dd][64 + tx * 4];
                float av[8] = {a0.x, a0.y, a0.z, a0.w, a1.x, a1.y, a1.z, a1.w};
                float bv[8] = {b0.x, b0.y, b0.z, b0.w, b1.x, b1.y, b1.z, b1.w};
                #pragma unroll
                for (int i = 0; i < 8; ++i)
                    #pragma unroll
                    for (int j = 0; j < 8; ++j)
                        acc[i][j] = __builtin_fmaf(av[i], bv[j], acc[i][j]);
            }
        }
        #pragma unroll
        for (int j = 0; j < 8; ++j) {
            int cj = (j < 4) ? (tx * 4 + j) : (64 + tx * 4 + (j - 4));
            int k = kbase + kt + cj;
            #pragma unroll
            for (int i = 0; i < 8; ++i) {
                float s = __builtin_fmaf(-2.0f, acc[i][j], Sr[i]);
                if (s < bval[i]) { bval[i] = s; bidx[i] = k; }
            }
        }
    }
    #pragma unroll
    for (int i = 0; i < 8; ++i) {
        float v = bval[i];
        int ix = bidx[i];
        #pragma unroll
        for (int off = 8; off > 0; off >>= 1) {
            float ov = __shfl_xor(v, off, 16);
            int oi = __shfl_xor(ix, off, 16);
            if (ov < v || (ov == v && oi < ix)) { v = ov; ix = oi; }
        }
        if (tx == 0) {
            unsigned u = __float_as_uint(v);
            unsigned key = (u & 0x80000000u) ? ~u : (u | 0x80000000u);
            u64 pk = ((u64)key << 32) | (unsigned)ix;
            atomicMin(&best[rowid[i]], pk);
        }
    }
}

__global__ void finalize_kernel(const float* __restrict__ lat,
                                const float* __restrict__ cb,
                                const u64* __restrict__ best,
                                float* __restrict__ out_q,
                                float* __restrict__ out_idx,
                                float* __restrict__ loss_accum) {
    int n = blockIdx.x;
    int t = threadIdx.x;
    int idx = (int)(best[n] & 0xFFFFFFFFULL);
    const float2 q = ((const float2*)(cb + (size_t)idx * DIM))[t];
    const float2 l = ((const float2*)(lat + (size_t)n * DIM))[t];
    ((float2*)(out_q + (size_t)n * DIM))[t] = q;
    float dx = l.x - q.x, dy = l.y - q.y;
    float local = dx * dx + dy * dy;
    #pragma unroll
    for (int off = 32; off > 0; off >>= 1) local += __shfl_down(local, off);
    __shared__ float wsum[4];
    if ((t & 63) == 0) wsum[t >> 6] = local;
    __syncthreads();
    if (t == 0) {
        atomicAdd(loss_accum, wsum[0] + wsum[1] + wsum[2] + wsum[3]);
        out_idx[n] = (float)idx;
    }
}

__global__ void write_loss_kernel(const float* __restrict__ loss_accum,
                                  float* __restrict__ out_loss) {
    *out_loss = (1.0f + BETA) * (*loss_accum) * (1.0f / (float)((size_t)NROWS * DIM));
}

// ---------------- launch ----------------

extern "C" void kernel_launch(void* const* d_in, const int* in_sizes, int n_in,
                              void* d_out, int out_size, void* d_ws, size_t ws_size,
                              hipStream_t stream) {
    const float* lat = (const float*)d_in[0];   // [8,1024,512] f32
    const float* cb  = (const float*)d_in[1];   // [8192,512] f32

    float* out = (float*)d_out;
    float* out_q    = out;
    float* out_loss = out + (size_t)NROWS * DIM;
    float* out_idx  = out_loss + 1;

    char* ws = (char*)d_ws;

    // fast-path layout (same sizes as rounds 7-13)
    const size_t MATB = (size_t)NROWS * DIM * 2;            // 8 MiB per bf16 matrix
    unsigned short* Atile = (unsigned short*)(ws);
    unsigned short* Btile = (unsigned short*)(ws + MATB);
    float4* top2        = (float4*)(ws + 2 * MATB);         // 16 MiB
    char* tail          = ws + 2 * MATB + (size_t)NROWS * 128 * 16;
    float* SrowF        = (float*)tail;                     // 32 KiB
    int*   idxfinal     = (int*)(tail + 32768);             // 32 KiB
    float* lossF        = (float*)(tail + 65536);           // 4 B
    const size_t REQ    = (size_t)(tail - ws) + 65536 + 64;

    if (ws_size >= REQ) {
        hipLaunchKernelGGL(convert_kernel, dim3(2 * NROWS * 64 / 256), dim3(256), 0, stream,
                           lat, cb, Atile, Btile, lossF);
        hipLaunchKernelGGL(rownorm_kernel, dim3(NROWS / 4), dim3(256), 0, stream, lat, SrowF);
        hipLaunchKernelGGL(mfma_dist_kernel, dim3(256), dim3(512),
                           0, stream, Atile, Btile, top2);
        hipLaunchKernelGGL(select_rescore_kernel, dim3(NROWS), dim3(256), 0, stream,
                           lat, cb, SrowF, top2, idxfinal);
        hipLaunchKernelGGL(finalize_idx_kernel, dim3(NROWS), dim3(256), 0, stream,
                           lat, cb, idxfinal, out_q, out_idx, lossF);
        hipLaunchKernelGGL(write_loss_kernel, dim3(1), dim3(1), 0, stream, lossF, out_loss);
    } else {
        // round-3 verified fallback
        u64*   best       = (u64*)(ws + 0);
        float* Srow       = (float*)(ws + 65536);
        float* loss_accum = (float*)(ws + 98304);
        hipLaunchKernelGGL(init_ws_kernel, dim3(32), dim3(256), 0, stream, best, loss_accum);
        hipLaunchKernelGGL(rownorm_kernel, dim3(NROWS / 4), dim3(256), 0, stream, lat, Srow);
        hipLaunchKernelGGL(dist_argmin_kernel, dim3(NROWS / BM, KCODES / KCHUNK), dim3(256),
                           0, stream, lat, cb, Srow, best);
        hipLaunchKernelGGL(finalize_kernel, dim3(NROWS), dim3(256), 0, stream,
                           lat, cb, best, out_q, out_idx, loss_accum);
        hipLaunchKernelGGL(write_loss_kernel, dim3(1), dim3(1), 0, stream, loss_accum, out_loss);
    }
}

// Round 15
// 731.872 us; speedup vs baseline: 1.0599x; 1.0565x over previous
//
#include <hip/hip_runtime.h>
#include <stdint.h>

#define NROWS 8192
#define KCODES 8192
#define DIM 512
#define BETA 0.25f

// fallback fp32 path tiling
#define BM 128
#define BN 128
#define BD 16
#define KCHUNK 512

// fast path: hi*hi screen error <= ~4e-4 worst-case; margin = 2x
#define MARGIN_T 8.0e-4f
#define MAXCAND 32

typedef unsigned long long u64;
typedef __attribute__((ext_vector_type(8))) short bf16x8;
typedef __attribute__((ext_vector_type(4))) float f32x4;
typedef __attribute__((ext_vector_type(8))) unsigned short us8;

// ---------------- shared helpers ----------------

__device__ inline unsigned short f2bf_rne(float x) {
    union { float f; unsigned u; } v; v.f = x;
    unsigned r = v.u + 0x7FFFu + ((v.u >> 16) & 1u);
    return (unsigned short)(r >> 16);
}
__device__ inline bool lexlt(float av, int ai, float bv, int bi) {
    return (av < bv) || (av == bv && ai < bi);
}
__device__ inline void ins2(float& v1, int& i1, float& v2, int& i2, float nv, int ni) {
    if (lexlt(nv, ni, v1, i1)) { v2 = v1; i2 = i1; v1 = nv; i1 = ni; }
    else if (lexlt(nv, ni, v2, i2)) { v2 = nv; i2 = ni; }
}

// ================= FAST PATH =================

// 128x128 tile, BK=64, 4 waves (2x2, 64x64 each), single 32 KiB LDS,
// 2-barrier loop, 4 blocks/CU. Stages DIRECTLY from d_in (fp32): global
// float4 loads -> in-register RNE bf16 conversion -> swizzled ds_write_b128.
// LDS image (and thus all screen values) bit-identical to the round-9/10
// verified kernel. Screen = hi*hi bf16; margin + exact rescore downstream.
__global__ __launch_bounds__(256, 4) void mfma_dist_kernel(
        const float* __restrict__ lat, const float* __restrict__ cb,
        float4* __restrict__ top2) {
    __shared__ unsigned short sA[128][64];   // 16 KiB
    __shared__ unsigned short sB[128][64];   // 16 KiB
    // XCD supertile mapping (as rounds 9/10)
    const int bid = blockIdx.x;
    const int xcd = bid & 7;
    const int j = bid >> 3;            // 0..511
    const int gg = j >> 5;             // 0..15
    const int u = j & 31;
    const int bx = gg * 4 + (u & 3);   // 0..63
    const int by = xcd * 8 + (u >> 2); // 0..63
    const int row0 = bx * 128, col0 = by * 128;
    const int tid = threadIdx.x;
    const int w = tid >> 6, l = tid & 63;
    const int wm = w >> 1, wn = w & 1;          // 2x2 wave grid
    const int g = l >> 4, c = l & 15;

    f32x4 acc[4][4];
    #pragma unroll
    for (int a = 0; a < 4; ++a)
        #pragma unroll
        for (int b = 0; b < 4; ++b)
            acc[a][b] = (f32x4){0.f, 0.f, 0.f, 0.f};

    for (int kt = 0; kt < 8; ++kt) {
        const int d0 = kt * 64;
        // stage: slot s = tid + 256*i -> r = s>>3, cdst = s&7;
        // LDS[r][cdst*8..] <- RNE(src[r][d0 + (cdst^(r&7))*8 ..])  (swizzled image)
        #pragma unroll
        for (int i = 0; i < 4; ++i) {
            const int s = tid + 256 * i;
            const int r = s >> 3;
            const int cd = s & 7;
            const int cs8 = cd ^ (r & 7);
            const float4* pa = (const float4*)(lat + (size_t)(row0 + r) * DIM + d0 + cs8 * 8);
            const float4* pb = (const float4*)(cb + (size_t)(col0 + r) * DIM + d0 + cs8 * 8);
            float4 va0 = pa[0], va1 = pa[1];
            float4 vb0 = pb[0], vb1 = pb[1];
            us8 ha, hb;
            ha[0] = f2bf_rne(va0.x); ha[1] = f2bf_rne(va0.y);
            ha[2] = f2bf_rne(va0.z); ha[3] = f2bf_rne(va0.w);
            ha[4] = f2bf_rne(va1.x); ha[5] = f2bf_rne(va1.y);
            ha[6] = f2bf_rne(va1.z); ha[7] = f2bf_rne(va1.w);
            hb[0] = f2bf_rne(vb0.x); hb[1] = f2bf_rne(vb0.y);
            hb[2] = f2bf_rne(vb0.z); hb[3] = f2bf_rne(vb0.w);
            hb[4] = f2bf_rne(vb1.x); hb[5] = f2bf_rne(vb1.y);
            hb[6] = f2bf_rne(vb1.z); hb[7] = f2bf_rne(vb1.w);
            *(us8*)&sA[r][cd * 8] = ha;
            *(us8*)&sB[r][cd * 8] = hb;
        }
        __syncthreads();   // tile staged and visible
        #pragma unroll
        for (int kk = 0; kk < 2; ++kk) {
            const int colbase = kk * 32 + g * 8;
            bf16x8 af[4], bfr[4];
            #pragma unroll
            for (int f = 0; f < 4; ++f) {
                int ra = wm * 64 + f * 16 + c;
                int ca = colbase ^ ((ra & 7) << 3);   // swizzled read (unchanged)
                af[f] = *(const bf16x8*)&sA[ra][ca];
                int rb = wn * 64 + f * 16 + c;
                int cb2 = colbase ^ ((rb & 7) << 3);
                bfr[f] = *(const bf16x8*)&sB[rb][cb2];
            }
            #pragma unroll
            for (int fm = 0; fm < 4; ++fm)
                #pragma unroll
                for (int fn = 0; fn < 4; ++fn)
                    acc[fm][fn] = __builtin_amdgcn_mfma_f32_16x16x32_bf16(
                        af[fm], bfr[fn], acc[fm][fn], 0, 0, 0);
        }
        __syncthreads();   // all reads done; safe to overwrite next step
    }

    // epilogue: per-row top-2 over this wave's 64 codes (lex (t,idx)); t=-2*acc
    #pragma unroll
    for (int fm = 0; fm < 4; ++fm) {
        #pragma unroll
        for (int r = 0; r < 4; ++r) {
            float v1 = -2.0f * acc[fm][0][r];
            int i1 = col0 + wn * 64 + c;
            float v2 = 3.4e38f; int i2 = 0x7FFFFFFF;
            #pragma unroll
            for (int fn = 1; fn < 4; ++fn) {
                float nv = -2.0f * acc[fm][fn][r];
                int ni = col0 + wn * 64 + fn * 16 + c;
                ins2(v1, i1, v2, i2, nv, ni);
            }
            #pragma unroll
            for (int mask = 1; mask <= 8; mask <<= 1) {
                float o1 = __shfl_xor(v1, mask); int oi1 = __shfl_xor(i1, mask);
                float o2 = __shfl_xor(v2, mask); int oi2 = __shfl_xor(i2, mask);
                ins2(v1, i1, v2, i2, o1, oi1);
                ins2(v1, i1, v2, i2, o2, oi2);
            }
            if (c == 0) {
                int row = row0 + wm * 64 + fm * 16 + g * 4 + r;
                float4 e;
                e.x = v1; e.y = __int_as_float(i1);
                e.z = v2; e.w = __int_as_float(i2);
                top2[(size_t)row * 128 + by * 2 + wn] = e;
            }
        }
    }
}

// FUSED per-row kernel: numpy-exact row norm (in-block), global approx min
// over 256 stored entries, margin candidates, exact fp32-chain rescore,
// lexicographic winner; then gather codebook[idx] -> out_q, loss accumulate,
// write float index. One block per row.
__global__ __launch_bounds__(256) void select_finalize_kernel(
        const float* __restrict__ lat, const float* __restrict__ cb,
        const float4* __restrict__ top2,
        float* __restrict__ out_q, float* __restrict__ out_idx,
        float* __restrict__ loss_accum) {
    __shared__ float fr[DIM];
    __shared__ float svals[128];
    __shared__ int sidx[128];
    __shared__ int scnt;
    __shared__ int scand[MAXCAND];
    __shared__ float cs[MAXCAND];
    __shared__ int ck[MAXCAND];
    __shared__ float sS;
    __shared__ int sbi;
    __shared__ float wsum[4];
    const int n = blockIdx.x;
    const int t = threadIdx.x;

    fr[t] = lat[(size_t)n * DIM + t];
    fr[t + 256] = lat[(size_t)n * DIM + t + 256];
    if (t == 0) scnt = 0;

    float4 e;
    if (t < 128) {
        e = top2[(size_t)n * 128 + t];
        float pv = e.x; int pi = __float_as_int(e.y);
        int e2 = __float_as_int(e.w);
        if (lexlt(e.z, e2, pv, pi)) { pv = e.z; pi = e2; }
        svals[t] = pv; sidx[t] = pi;
    }
    __syncthreads();

    // numpy-exact pairwise sum of fl32(f_i^2), n=512 (same tree as verified):
    // 4 blocks of 128 (8 accumulators x 16-term chains), pairwise combine.
    if (t < 32) {
        const int m = t >> 3;
        const int j = t & 7;
        const float* b = fr + 128 * m + j;
        float r = b[0] * b[0];
        #pragma unroll
        for (int q = 1; q < 16; ++q) { float x = b[8 * q]; r += x * x; }
        float s1 = r + __shfl_down(r, 1);
        float s2 = s1 + __shfl_down(s1, 2);
        float s3 = s2 + __shfl_down(s2, 4);
        float x0 = s3 + __shfl_down(s3, 8);
        float S = x0 + __shfl_down(x0, 16);
        if (t == 0) sS = S;
    }

    // global approx min (lexicographic) over the 128 folded entries
    for (int s = 64; s > 0; s >>= 1) {
        if (t < s && lexlt(svals[t + s], sidx[t + s], svals[t], sidx[t])) {
            svals[t] = svals[t + s]; sidx[t] = sidx[t + s];
        }
        __syncthreads();
    }
    const float gthr = svals[0] + MARGIN_T;
    __syncthreads();
    if (t < 128) {
        if (e.x <= gthr) {
            int p = atomicAdd(&scnt, 1);
            if (p < MAXCAND) scand[p] = __float_as_int(e.y);
        }
        if (e.z <= gthr) {
            int p = atomicAdd(&scnt, 1);
            if (p < MAXCAND) scand[p] = __float_as_int(e.w);
        }
    }
    __syncthreads();   // also makes sS visible
    int m = scnt < MAXCAND ? scnt : MAXCAND;
    if (t < m) {
        int k = scand[t];
        const float* crow = cb + (size_t)k * DIM;
        float acc = 0.0f;
        for (int d = 0; d < DIM; d += 4) {   // exact ascending-d FMA chain
            float4 b = *(const float4*)(crow + d);
            acc = __builtin_fmaf(fr[d + 0], b.x, acc);
            acc = __builtin_fmaf(fr[d + 1], b.y, acc);
            acc = __builtin_fmaf(fr[d + 2], b.z, acc);
            acc = __builtin_fmaf(fr[d + 3], b.w, acc);
        }
        cs[t] = __builtin_fmaf(-2.0f, acc, sS);
        ck[t] = k;
    }
    __syncthreads();
    if (t == 0) {
        float bv = cs[0]; int bi = ck[0];
        for (int q = 1; q < m; ++q)
            if (lexlt(cs[q], ck[q], bv, bi)) { bv = cs[q]; bi = ck[q]; }
        sbi = bi;
    }
    __syncthreads();

    // finalize: gather winner row, write out_q, loss partial, float index
    const int idx = sbi;
    const float2 q = ((const float2*)(cb + (size_t)idx * DIM))[t];
    const float2 lv = { fr[2 * t], fr[2 * t + 1] };
    ((float2*)(out_q + (size_t)n * DIM))[t] = q;
    float dx = lv.x - q.x, dy = lv.y - q.y;
    float local = dx * dx + dy * dy;
    #pragma unroll
    for (int off = 32; off > 0; off >>= 1) local += __shfl_down(local, off);
    if ((t & 63) == 0) wsum[t >> 6] = local;
    __syncthreads();
    if (t == 0) {
        atomicAdd(loss_accum, wsum[0] + wsum[1] + wsum[2] + wsum[3]);
        out_idx[n] = (float)idx;
    }
}

__global__ void write_loss_kernel(const float* __restrict__ loss_accum,
                                  float* __restrict__ out_loss) {
    *out_loss = (1.0f + BETA) * (*loss_accum) * (1.0f / (float)((size_t)NROWS * DIM));
}

// ================= FALLBACK (round-3 verified) =================

__global__ void init_ws_kernel(u64* __restrict__ best, float* __restrict__ loss_accum) {
    int i = blockIdx.x * blockDim.x + threadIdx.x;
    if (i < NROWS) best[i] = 0xFFFFFFFFFFFFFFFFULL;
    if (i == 0) *loss_accum = 0.0f;
}

__global__ __launch_bounds__(256) void rownorm_kernel(const float* __restrict__ lat,
                                                      float* __restrict__ Srow) {
    __shared__ float buf[4][DIM];
    const int w = threadIdx.x >> 6;
    const int lane = threadIdx.x & 63;
    const int n = blockIdx.x * 4 + w;
    {
        const float4* p = (const float4*)(lat + (size_t)n * DIM);
        float4 v0 = p[lane * 2];
        float4 v1 = p[lane * 2 + 1];
        float4* q = (float4*)buf[w];
        q[lane * 2] = v0;
        q[lane * 2 + 1] = v1;
    }
    __syncthreads();
    if (lane < 32) {
        const int m = lane >> 3;
        const int j = lane & 7;
        const float* b = buf[w] + 128 * m + j;
        float r = b[0] * b[0];
        #pragma unroll
        for (int t = 1; t < 16; ++t) { float x = b[8 * t]; r += x * x; }
        float s1 = r + __shfl_down(r, 1);
        float s2 = s1 + __shfl_down(s1, 2);
        float s3 = s2 + __shfl_down(s2, 4);
        float x0 = s3 + __shfl_down(s3, 8);
        float S = x0 + __shfl_down(x0, 16);
        if (lane == 0) Srow[n] = S;
    }
}

__global__ __launch_bounds__(256) void dist_argmin_kernel(
        const float* __restrict__ lat, const float* __restrict__ cb,
        const float* __restrict__ Srow, u64* __restrict__ best) {
    __shared__ float As[BD][BM];
    __shared__ float Bs[BD][BN];
    const int tid = threadIdx.x;
    const int tx = tid & 15;
    const int ty = tid >> 4;
    const int row0 = blockIdx.x * BM;
    const int kbase = blockIdx.y * KCHUNK;

    int rowid[8];
    float Sr[8];
    #pragma unroll
    for (int i = 0; i < 8; ++i) {
        rowid[i] = row0 + ((i < 4) ? (ty * 4 + i) : (64 + ty * 4 + (i - 4)));
        Sr[i] = Srow[rowid[i]];
    }
    float bval[8];
    int bidx[8];
    #pragma unroll
    for (int i = 0; i < 8; ++i) { bval[i] = 3.4e38f; bidx[i] = 0; }

    for (int kt = 0; kt < KCHUNK; kt += BN) {
        float acc[8][8];
        #pragma unroll
        for (int i = 0; i < 8; ++i)
            #pragma unroll
            for (int j = 0; j < 8; ++j) acc[i][j] = 0.0f;
        for (int d0 = 0; d0 < DIM; d0 += BD) {
            __syncthreads();
            #pragma unroll
            for (int u = 0; u < 2; ++u) {
                int f = tid * 2 + u;
                int r = f >> 2;
                int dq = (f & 3) * 4;
                float4 va = *(const float4*)(lat + (size_t)(row0 + r) * DIM + d0 + dq);
                As[dq + 0][r] = va.x; As[dq + 1][r] = va.y;
                As[dq + 2][r] = va.z; As[dq + 3][r] = va.w;
                float4 vb = *(const float4*)(cb + (size_t)(kbase + kt + r) * DIM + d0 + dq);
                Bs[dq + 0][r] = vb.x; Bs[dq + 1][r] = vb.y;
                Bs[dq + 2][r] = vb.z; Bs[dq + 3][r] = vb.w;
            }
            __syncthreads();
            #pragma unroll
            for (int dd = 0; dd < BD; ++dd) {
                float4 a0 = *(const float4*)&As[dd][ty * 4];
                float4 a1 = *(const float4*)&As[dd][64 + ty * 4];
                float4 b0 = *(const float4*)&Bs[dd][tx * 4];
                float4 b1 = *(const float4*)&Bs[dd][64 + tx * 4];
                float av[8] = {a0.x, a0.y, a0.z, a0.w, a1.x, a1.y, a1.z, a1.w};
                float bv[8] = {b0.x, b0.y, b0.z, b0.w, b1.x, b1.y, b1.z, b1.w};
                #pragma unroll
                for (int i = 0; i < 8; ++i)
                    #pragma unroll
                    for (int j = 0; j < 8; ++j)
                        acc[i][j] = __builtin_fmaf(av[i], bv[j], acc[i][j]);
            }
        }
        #pragma unroll
        for (int j = 0; j < 8; ++j) {
            int cj = (j < 4) ? (tx * 4 + j) : (64 + tx * 4 + (j - 4));
            int k = kbase + kt + cj;
            #pragma unroll
            for (int i = 0; i < 8; ++i) {
                float s = __builtin_fmaf(-2.0f, acc[i][j], Sr[i]);
                if (s < bval[i]) { bval[i] = s; bidx[i] = k; }
            }
        }
    }
    #pragma unroll
    for (int i = 0; i < 8; ++i) {
        float v = bval[i];
        int ix = bidx[i];
        #pragma unroll
        for (int off = 8; off > 0; off >>= 1) {
            float ov = __shfl_xor(v, off, 16);
            int oi = __shfl_xor(ix, off, 16);
            if (ov < v || (ov == v && oi < ix)) { v = ov; ix = oi; }
        }
        if (tx == 0) {
            unsigned u = __float_as_uint(v);
            unsigned key = (u & 0x80000000u) ? ~u : (u | 0x80000000u);
            u64 pk = ((u64)key << 32) | (unsigned)ix;
            atomicMin(&best[rowid[i]], pk);
        }
    }
}

__global__ void finalize_kernel(const float* __restrict__ lat,
                                const float* __restrict__ cb,
                                const u64* __restrict__ best,
                                float* __restrict__ out_q,
                                float* __restrict__ out_idx,
                                float* __restrict__ loss_accum) {
    int n = blockIdx.x;
    int t = threadIdx.x;
    int idx = (int)(best[n] & 0xFFFFFFFFULL);
    const float2 q = ((const float2*)(cb + (size_t)idx * DIM))[t];
    const float2 l = ((const float2*)(lat + (size_t)n * DIM))[t];
    ((float2*)(out_q + (size_t)n * DIM))[t] = q;
    float dx = l.x - q.x, dy = l.y - q.y;
    float local = dx * dx + dy * dy;
    #pragma unroll
    for (int off = 32; off > 0; off >>= 1) local += __shfl_down(local, off);
    __shared__ float wsum[4];
    if ((t & 63) == 0) wsum[t >> 6] = local;
    __syncthreads();
    if (t == 0) {
        atomicAdd(loss_accum, wsum[0] + wsum[1] + wsum[2] + wsum[3]);
        out_idx[n] = (float)idx;
    }
}

// ---------------- launch ----------------

extern "C" void kernel_launch(void* const* d_in, const int* in_sizes, int n_in,
                              void* d_out, int out_size, void* d_ws, size_t ws_size,
                              hipStream_t stream) {
    const float* lat = (const float*)d_in[0];   // [8,1024,512] f32
    const float* cb  = (const float*)d_in[1];   // [8192,512] f32

    float* out = (float*)d_out;
    float* out_q    = out;
    float* out_loss = out + (size_t)NROWS * DIM;
    float* out_idx  = out_loss + 1;

    char* ws = (char*)d_ws;

    // fast-path layout: only top2 (16 MiB) + loss accumulator
    float4* top2 = (float4*)ws;
    float* lossF = (float*)(ws + (size_t)NROWS * 128 * 16);
    const size_t REQ = (size_t)NROWS * 128 * 16 + 64;

    if (ws_size >= REQ) {
        hipMemsetAsync(lossF, 0, sizeof(float), stream);
        hipLaunchKernelGGL(mfma_dist_kernel, dim3((NROWS / 128) * (KCODES / 128)), dim3(256),
                           0, stream, lat, cb, top2);
        hipLaunchKernelGGL(select_finalize_kernel, dim3(NROWS), dim3(256), 0, stream,
                           lat, cb, top2, out_q, out_idx, lossF);
        hipLaunchKernelGGL(write_loss_kernel, dim3(1), dim3(1), 0, stream, lossF, out_loss);
    } else {
        // round-3 verified fallback
        u64*   best       = (u64*)(ws + 0);
        float* Srow       = (float*)(ws + 65536);
        float* loss_accum = (float*)(ws + 98304);
        hipLaunchKernelGGL(init_ws_kernel, dim3(32), dim3(256), 0, stream, best, loss_accum);
        hipLaunchKernelGGL(rownorm_kernel, dim3(NROWS / 4), dim3(256), 0, stream, lat, Srow);
        hipLaunchKernelGGL(dist_argmin_kernel, dim3(NROWS / BM, KCODES / KCHUNK), dim3(256),
                           0, stream, lat, cb, Srow, best);
        hipLaunchKernelGGL(finalize_kernel, dim3(NROWS), dim3(256), 0, stream,
                           lat, cb, best, out_q, out_idx, loss_accum);
        hipLaunchKernelGGL(write_loss_kernel, dim3(1), dim3(1), 0, stream, loss_accum, out_loss);
    }
}

// Round 16
// 687.440 us; speedup vs baseline: 1.1284x; 1.0646x over previous
//
#include <hip/hip_runtime.h>
#include <stdint.h>

#define NROWS 8192
#define KCODES 8192
#define DIM 512
#define BETA 0.25f

// fallback fp32 path tiling
#define BM 128
#define BN 128
#define BD 16
#define KCHUNK 512

// fast path: hi*hi screen error <= ~4e-4 worst-case; margin = 2x
#define MARGIN_T 8.0e-4f
#define MAXCAND 32

typedef unsigned long long u64;
typedef __attribute__((ext_vector_type(8))) short bf16x8;
typedef __attribute__((ext_vector_type(4))) float f32x4;
typedef __attribute__((ext_vector_type(4))) unsigned short us4;

// ---------------- shared helpers ----------------

__device__ inline unsigned short f2bf_rne(float x) {
    union { float f; unsigned u; } v; v.f = x;
    unsigned r = v.u + 0x7FFFu + ((v.u >> 16) & 1u);
    return (unsigned short)(r >> 16);
}
__device__ inline bool lexlt(float av, int ai, float bv, int bi) {
    return (av < bv) || (av == bv && ai < bi);
}
__device__ inline void ins2(float& v1, int& i1, float& v2, int& i2, float nv, int ni) {
    if (lexlt(nv, ni, v1, i1)) { v2 = v1; i2 = i1; v1 = nv; i1 = ni; }
    else if (lexlt(nv, ni, v2, i2)) { v2 = nv; i2 = ni; }
}
__device__ inline void gload_lds16(const void* g, void* l) {
    __builtin_amdgcn_global_load_lds(
        (const __attribute__((address_space(1))) void*)g,
        (__attribute__((address_space(3))) void*)l, 16, 0, 0);
}

// ================= FAST PATH =================

// f32 -> bf16 hi, PRE-TILED + PRE-SWIZZLED (round-10 verified):
//   tiled[(panel*8 + kt)*1024 + r*8 + cdst] (16B chunks)
//     = src[panel*128 + r][kt*64 + (cdst ^ (r&7))*8 .. +8]   (bf16)
// Also zeroes the loss accumulator (thread 0).
__global__ __launch_bounds__(256) void convert_kernel(
        const float* __restrict__ lat, const float* __restrict__ cb,
        unsigned short* __restrict__ Atile, unsigned short* __restrict__ Btile,
        float* __restrict__ loss_accum) {
    size_t t = (size_t)blockIdx.x * 256 + threadIdx.x;   // one 8-elem chunk each
    if (t == 0) *loss_accum = 0.0f;
    const size_t half = (size_t)NROWS * 64;              // chunks per matrix
    const float* src; unsigned short* dst;
    if (t < half) { src = lat; dst = Atile; }
    else { src = cb; dst = Btile; t -= half; }
    const int row   = (int)(t >> 6);       // 0..8191
    const int csrc  = (int)(t & 63);       // source chunk 0..63
    const int panel = row >> 7;            // 0..63
    const int r     = row & 127;
    const int kt    = csrc >> 3;           // 0..7
    const int cdst  = (csrc & 7) ^ (r & 7);
    const float4 v0 = *(const float4*)(src + (size_t)row * DIM + csrc * 8);
    const float4 v1 = *(const float4*)(src + (size_t)row * DIM + csrc * 8 + 4);
    us4 h0, h1;
    h0.x = f2bf_rne(v0.x); h0.y = f2bf_rne(v0.y); h0.z = f2bf_rne(v0.z); h0.w = f2bf_rne(v0.w);
    h1.x = f2bf_rne(v1.x); h1.y = f2bf_rne(v1.y); h1.z = f2bf_rne(v1.z); h1.w = f2bf_rne(v1.w);
    unsigned short* o = dst + (((size_t)(panel * 8 + kt) * 128 + r) * 8 + cdst) * 8;
    *(us4*)o = h0;
    *(us4*)(o + 4) = h1;
}

// Round-9/10 verified structure (best measured: 597 us): 128x128 tile,
// BK=64, 4 waves (2x2, 64x64 each), single 32 KiB LDS, 2-barrier loop,
// 4 blocks/CU, lane-linear gload_lds from pre-tiled operands, XCD supertile.
// Screen = hi*hi bf16; margin + exact rescore downstream.
__global__ __launch_bounds__(256, 4) void mfma_dist_kernel(
        const unsigned short* __restrict__ Atile, const unsigned short* __restrict__ Btile,
        float4* __restrict__ top2) {
    __shared__ unsigned short sA[128][64];   // 16 KiB
    __shared__ unsigned short sB[128][64];   // 16 KiB
    const int bid = blockIdx.x;
    const int xcd = bid & 7;
    const int j = bid >> 3;            // 0..511
    const int gg = j >> 5;             // 0..15
    const int u = j & 31;
    const int bx = gg * 4 + (u & 3);   // 0..63
    const int by = xcd * 8 + (u >> 2); // 0..63
    const int col0 = by * 128;
    const int row0 = bx * 128;
    const int tid = threadIdx.x;
    const int w = tid >> 6, l = tid & 63;
    const int wm = w >> 1, wn = w & 1;          // 2x2 wave grid
    const int g = l >> 4, c = l & 15;

    f32x4 acc[4][4];
    #pragma unroll
    for (int a = 0; a < 4; ++a)
        #pragma unroll
        for (int b = 0; b < 4; ++b)
            acc[a][b] = (f32x4){0.f, 0.f, 0.f, 0.f};

    for (int kt = 0; kt < 8; ++kt) {
        const unsigned short* At = Atile + (size_t)(bx * 8 + kt) * (128 * 64);
        const unsigned short* Bt = Btile + (size_t)(by * 8 + kt) * (128 * 64);
        // stage: lane-linear contiguous 1 KiB bursts (base + 16B*lane)
        #pragma unroll
        for (int i = 0; i < 4; ++i) {
            const int r0 = w * 32 + i * 8;
            gload_lds16(At + (size_t)r0 * 64 + l * 8, &sA[r0][0]);
            gload_lds16(Bt + (size_t)r0 * 64 + l * 8, &sB[r0][0]);
        }
        __syncthreads();   // drain: tile staged and visible
        #pragma unroll
        for (int kk = 0; kk < 2; ++kk) {
            const int colbase = kk * 32 + g * 8;
            bf16x8 af[4], bfr[4];
            #pragma unroll
            for (int f = 0; f < 4; ++f) {
                int ra = wm * 64 + f * 16 + c;
                int ca = colbase ^ ((ra & 7) << 3);   // swizzled read
                af[f] = *(const bf16x8*)&sA[ra][ca];
                int rb = wn * 64 + f * 16 + c;
                int cb2 = colbase ^ ((rb & 7) << 3);
                bfr[f] = *(const bf16x8*)&sB[rb][cb2];
            }
            #pragma unroll
            for (int fm = 0; fm < 4; ++fm)
                #pragma unroll
                for (int fn = 0; fn < 4; ++fn)
                    acc[fm][fn] = __builtin_amdgcn_mfma_f32_16x16x32_bf16(
                        af[fm], bfr[fn], acc[fm][fn], 0, 0, 0);
        }
        __syncthreads();   // all reads done; safe to overwrite next step
    }

    // epilogue: per-row top-2 over this wave's 64 codes (lex (t,idx)); t=-2*acc
    #pragma unroll
    for (int fm = 0; fm < 4; ++fm) {
        #pragma unroll
        for (int r = 0; r < 4; ++r) {
            float v1 = -2.0f * acc[fm][0][r];
            int i1 = col0 + wn * 64 + c;
            float v2 = 3.4e38f; int i2 = 0x7FFFFFFF;
            #pragma unroll
            for (int fn = 1; fn < 4; ++fn) {
                float nv = -2.0f * acc[fm][fn][r];
                int ni = col0 + wn * 64 + fn * 16 + c;
                ins2(v1, i1, v2, i2, nv, ni);
            }
            #pragma unroll
            for (int mask = 1; mask <= 8; mask <<= 1) {
                float o1 = __shfl_xor(v1, mask); int oi1 = __shfl_xor(i1, mask);
                float o2 = __shfl_xor(v2, mask); int oi2 = __shfl_xor(i2, mask);
                ins2(v1, i1, v2, i2, o1, oi1);
                ins2(v1, i1, v2, i2, o2, oi2);
            }
            if (c == 0) {
                int row = row0 + wm * 64 + fm * 16 + g * 4 + r;
                float4 e;
                e.x = v1; e.y = __int_as_float(i1);
                e.z = v2; e.w = __int_as_float(i2);
                top2[(size_t)row * 128 + by * 2 + wn] = e;
            }
        }
    }
}

// FUSED per-row tail (round-15 verified): numpy-exact row norm in-block,
// global approx min over 256 stored entries, margin candidates, exact
// fp32-chain rescore, lexicographic winner; then gather codebook[idx],
// loss accumulate, write float index. One block per row.
__global__ __launch_bounds__(256) void select_finalize_kernel(
        const float* __restrict__ lat, const float* __restrict__ cb,
        const float4* __restrict__ top2,
        float* __restrict__ out_q, float* __restrict__ out_idx,
        float* __restrict__ loss_accum) {
    __shared__ float fr[DIM];
    __shared__ float svals[128];
    __shared__ int sidx[128];
    __shared__ int scnt;
    __shared__ int scand[MAXCAND];
    __shared__ float cs[MAXCAND];
    __shared__ int ck[MAXCAND];
    __shared__ float sS;
    __shared__ int sbi;
    __shared__ float wsum[4];
    const int n = blockIdx.x;
    const int t = threadIdx.x;

    fr[t] = lat[(size_t)n * DIM + t];
    fr[t + 256] = lat[(size_t)n * DIM + t + 256];
    if (t == 0) scnt = 0;

    float4 e;
    if (t < 128) {
        e = top2[(size_t)n * 128 + t];
        float pv = e.x; int pi = __float_as_int(e.y);
        int e2 = __float_as_int(e.w);
        if (lexlt(e.z, e2, pv, pi)) { pv = e.z; pi = e2; }
        svals[t] = pv; sidx[t] = pi;
    }
    __syncthreads();

    // numpy-exact pairwise sum of fl32(f_i^2), n=512 (verified tree):
    if (t < 32) {
        const int m = t >> 3;
        const int j = t & 7;
        const float* b = fr + 128 * m + j;
        float r = b[0] * b[0];
        #pragma unroll
        for (int q = 1; q < 16; ++q) { float x = b[8 * q]; r += x * x; }
        float s1 = r + __shfl_down(r, 1);
        float s2 = s1 + __shfl_down(s1, 2);
        float s3 = s2 + __shfl_down(s2, 4);
        float x0 = s3 + __shfl_down(s3, 8);
        float S = x0 + __shfl_down(x0, 16);
        if (t == 0) sS = S;
    }

    for (int s = 64; s > 0; s >>= 1) {
        if (t < s && lexlt(svals[t + s], sidx[t + s], svals[t], sidx[t])) {
            svals[t] = svals[t + s]; sidx[t] = sidx[t + s];
        }
        __syncthreads();
    }
    const float gthr = svals[0] + MARGIN_T;
    __syncthreads();
    if (t < 128) {
        if (e.x <= gthr) {
            int p = atomicAdd(&scnt, 1);
            if (p < MAXCAND) scand[p] = __float_as_int(e.y);
        }
        if (e.z <= gthr) {
            int p = atomicAdd(&scnt, 1);
            if (p < MAXCAND) scand[p] = __float_as_int(e.w);
        }
    }
    __syncthreads();   // also makes sS visible
    int m = scnt < MAXCAND ? scnt : MAXCAND;
    if (t < m) {
        int k = scand[t];
        const float* crow = cb + (size_t)k * DIM;
        float acc = 0.0f;
        for (int d = 0; d < DIM; d += 4) {   // exact ascending-d FMA chain
            float4 b = *(const float4*)(crow + d);
            acc = __builtin_fmaf(fr[d + 0], b.x, acc);
            acc = __builtin_fmaf(fr[d + 1], b.y, acc);
            acc = __builtin_fmaf(fr[d + 2], b.z, acc);
            acc = __builtin_fmaf(fr[d + 3], b.w, acc);
        }
        cs[t] = __builtin_fmaf(-2.0f, acc, sS);
        ck[t] = k;
    }
    __syncthreads();
    if (t == 0) {
        float bv = cs[0]; int bi = ck[0];
        for (int q = 1; q < m; ++q)
            if (lexlt(cs[q], ck[q], bv, bi)) { bv = cs[q]; bi = ck[q]; }
        sbi = bi;
    }
    __syncthreads();

    const int idx = sbi;
    const float2 q = ((const float2*)(cb + (size_t)idx * DIM))[t];
    const float2 lv = { fr[2 * t], fr[2 * t + 1] };
    ((float2*)(out_q + (size_t)n * DIM))[t] = q;
    float dx = lv.x - q.x, dy = lv.y - q.y;
    float local = dx * dx + dy * dy;
    #pragma unroll
    for (int off = 32; off > 0; off >>= 1) local += __shfl_down(local, off);
    if ((t & 63) == 0) wsum[t >> 6] = local;
    __syncthreads();
    if (t == 0) {
        atomicAdd(loss_accum, wsum[0] + wsum[1] + wsum[2] + wsum[3]);
        out_idx[n] = (float)idx;
    }
}

__global__ void write_loss_kernel(const float* __restrict__ loss_accum,
                                  float* __restrict__ out_loss) {
    *out_loss = (1.0f + BETA) * (*loss_accum) * (1.0f / (float)((size_t)NROWS * DIM));
}

// ================= FALLBACK (round-3 verified) =================

__global__ void init_ws_kernel(u64* __restrict__ best, float* __restrict__ loss_accum) {
    int i = blockIdx.x * blockDim.x + threadIdx.x;
    if (i < NROWS) best[i] = 0xFFFFFFFFFFFFFFFFULL;
    if (i == 0) *loss_accum = 0.0f;
}

__global__ __launch_bounds__(256) void rownorm_kernel(const float* __restrict__ lat,
                                                      float* __restrict__ Srow) {
    __shared__ float buf[4][DIM];
    const int w = threadIdx.x >> 6;
    const int lane = threadIdx.x & 63;
    const int n = blockIdx.x * 4 + w;
    {
        const float4* p = (const float4*)(lat + (size_t)n * DIM);
        float4 v0 = p[lane * 2];
        float4 v1 = p[lane * 2 + 1];
        float4* q = (float4*)buf[w];
        q[lane * 2] = v0;
        q[lane * 2 + 1] = v1;
    }
    __syncthreads();
    if (lane < 32) {
        const int m = lane >> 3;
        const int j = lane & 7;
        const float* b = buf[w] + 128 * m + j;
        float r = b[0] * b[0];
        #pragma unroll
        for (int t = 1; t < 16; ++t) { float x = b[8 * t]; r += x * x; }
        float s1 = r + __shfl_down(r, 1);
        float s2 = s1 + __shfl_down(s1, 2);
        float s3 = s2 + __shfl_down(s2, 4);
        float x0 = s3 + __shfl_down(s3, 8);
        float S = x0 + __shfl_down(x0, 16);
        if (lane == 0) Srow[n] = S;
    }
}

__global__ __launch_bounds__(256) void dist_argmin_kernel(
        const float* __restrict__ lat, const float* __restrict__ cb,
        const float* __restrict__ Srow, u64* __restrict__ best) {
    __shared__ float As[BD][BM];
    __shared__ float Bs[BD][BN];
    const int tid = threadIdx.x;
    const int tx = tid & 15;
    const int ty = tid >> 4;
    const int row0 = blockIdx.x * BM;
    const int kbase = blockIdx.y * KCHUNK;

    int rowid[8];
    float Sr[8];
    #pragma unroll
    for (int i = 0; i < 8; ++i) {
        rowid[i] = row0 + ((i < 4) ? (ty * 4 + i) : (64 + ty * 4 + (i - 4)));
        Sr[i] = Srow[rowid[i]];
    }
    float bval[8];
    int bidx[8];
    #pragma unroll
    for (int i = 0; i < 8; ++i) { bval[i] = 3.4e38f; bidx[i] = 0; }

    for (int kt = 0; kt < KCHUNK; kt += BN) {
        float acc[8][8];
        #pragma unroll
        for (int i = 0; i < 8; ++i)
            #pragma unroll
            for (int j = 0; j < 8; ++j) acc[i][j] = 0.0f;
        for (int d0 = 0; d0 < DIM; d0 += BD) {
            __syncthreads();
            #pragma unroll
            for (int u = 0; u < 2; ++u) {
                int f = tid * 2 + u;
                int r = f >> 2;
                int dq = (f & 3) * 4;
                float4 va = *(const float4*)(lat + (size_t)(row0 + r) * DIM + d0 + dq);
                As[dq + 0][r] = va.x; As[dq + 1][r] = va.y;
                As[dq + 2][r] = va.z; As[dq + 3][r] = va.w;
                float4 vb = *(const float4*)(cb + (size_t)(kbase + kt + r) * DIM + d0 + dq);
                Bs[dq + 0][r] = vb.x; Bs[dq + 1][r] = vb.y;
                Bs[dq + 2][r] = vb.z; Bs[dq + 3][r] = vb.w;
            }
            __syncthreads();
            #pragma unroll
            for (int dd = 0; dd < BD; ++dd) {
                float4 a0 = *(const float4*)&As[dd][ty * 4];
                float4 a1 = *(const float4*)&As[dd][64 + ty * 4];
                float4 b0 = *(const float4*)&Bs[dd][tx * 4];
                float4 b1 = *(const float4*)&Bs[dd][64 + tx * 4];
                float av[8] = {a0.x, a0.y, a0.z, a0.w, a1.x, a1.y, a1.z, a1.w};
                float bv[8] = {b0.x, b0.y, b0.z, b0.w, b1.x, b1.y, b1.z, b1.w};
                #pragma unroll
                for (int i = 0; i < 8; ++i)
                    #pragma unroll
                    for (int j = 0; j < 8; ++j)
                        acc[i][j] = __builtin_fmaf(av[i], bv[j], acc[i][j]);
            }
        }
        #pragma unroll
        for (int j = 0; j < 8; ++j) {
            int cj = (j < 4) ? (tx * 4 + j) : (64 + tx * 4 + (j - 4));
            int k = kbase + kt + cj;
            #pragma unroll
            for (int i = 0; i < 8; ++i) {
                float s = __builtin_fmaf(-2.0f, acc[i][j], Sr[i]);
                if (s < bval[i]) { bval[i] = s; bidx[i] = k; }
            }
        }
    }
    #pragma unroll
    for (int i = 0; i < 8; ++i) {
        float v = bval[i];
        int ix = bidx[i];
        #pragma unroll
        for (int off = 8; off > 0; off >>= 1) {
            float ov = __shfl_xor(v, off, 16);
            int oi = __shfl_xor(ix, off, 16);
            if (ov < v || (ov == v && oi < ix)) { v = ov; ix = oi; }
        }
        if (tx == 0) {
            unsigned u = __float_as_uint(v);
            unsigned key = (u & 0x80000000u) ? ~u : (u | 0x80000000u);
            u64 pk = ((u64)key << 32) | (unsigned)ix;
            atomicMin(&best[rowid[i]], pk);
        }
    }
}

__global__ void finalize_kernel(const float* __restrict__ lat,
                                const float* __restrict__ cb,
                                const u64* __restrict__ best,
                                float* __restrict__ out_q,
                                float* __restrict__ out_idx,
                                float* __restrict__ loss_accum) {
    int n = blockIdx.x;
    int t = threadIdx.x;
    int idx = (int)(best[n] & 0xFFFFFFFFULL);
    const float2 q = ((const float2*)(cb + (size_t)idx * DIM))[t];
    const float2 l = ((const float2*)(lat + (size_t)n * DIM))[t];
    ((float2*)(out_q + (size_t)n * DIM))[t] = q;
    float dx = l.x - q.x, dy = l.y - q.y;
    float local = dx * dx + dy * dy;
    #pragma unroll
    for (int off = 32; off > 0; off >>= 1) local += __shfl_down(local, off);
    __shared__ float wsum[4];
    if ((t & 63) == 0) wsum[t >> 6] = local;
    __syncthreads();
    if (t == 0) {
        atomicAdd(loss_accum, wsum[0] + wsum[1] + wsum[2] + wsum[3]);
        out_idx[n] = (float)idx;
    }
}

// ---------------- launch ----------------

extern "C" void kernel_launch(void* const* d_in, const int* in_sizes, int n_in,
                              void* d_out, int out_size, void* d_ws, size_t ws_size,
                              hipStream_t stream) {
    const float* lat = (const float*)d_in[0];   // [8,1024,512] f32
    const float* cb  = (const float*)d_in[1];   // [8192,512] f32

    float* out = (float*)d_out;
    float* out_q    = out;
    float* out_loss = out + (size_t)NROWS * DIM;
    float* out_idx  = out_loss + 1;

    char* ws = (char*)d_ws;

    // fast-path layout
    const size_t MATB = (size_t)NROWS * DIM * 2;            // 8 MiB per bf16 matrix
    unsigned short* Atile = (unsigned short*)(ws);
    unsigned short* Btile = (unsigned short*)(ws + MATB);
    float4* top2 = (float4*)(ws + 2 * MATB);                // 16 MiB
    float* lossF = (float*)(ws + 2 * MATB + (size_t)NROWS * 128 * 16);
    const size_t REQ = 2 * MATB + (size_t)NROWS * 128 * 16 + 64;

    if (ws_size >= REQ) {
        hipLaunchKernelGGL(convert_kernel, dim3(2 * NROWS * 64 / 256), dim3(256), 0, stream,
                           lat, cb, Atile, Btile, lossF);
        hipLaunchKernelGGL(mfma_dist_kernel, dim3((NROWS / 128) * (KCODES / 128)), dim3(256),
                           0, stream, Atile, Btile, top2);
        hipLaunchKernelGGL(select_finalize_kernel, dim3(NROWS), dim3(256), 0, stream,
                           lat, cb, top2, out_q, out_idx, lossF);
        hipLaunchKernelGGL(write_loss_kernel, dim3(1), dim3(1), 0, stream, lossF, out_loss);
    } else {
        // round-3 verified fallback
        u64*   best       = (u64*)(ws + 0);
        float* Srow       = (float*)(ws + 65536);
        float* loss_accum = (float*)(ws + 98304);
        hipLaunchKernelGGL(init_ws_kernel, dim3(32), dim3(256), 0, stream, best, loss_accum);
        hipLaunchKernelGGL(rownorm_kernel, dim3(NROWS / 4), dim3(256), 0, stream, lat, Srow);
        hipLaunchKernelGGL(dist_argmin_kernel, dim3(NROWS / BM, KCODES / KCHUNK), dim3(256),
                           0, stream, lat, cb, Srow, best);
        hipLaunchKernelGGL(finalize_kernel, dim3(NROWS), dim3(256), 0, stream,
                           lat, cb, best, out_q, out_idx, loss_accum);
        hipLaunchKernelGGL(write_loss_kernel, dim3(1), dim3(1), 0, stream, loss_accum, out_loss);
    }
}